// Round 1
// 5338.763 us; speedup vs baseline: 4.7953x; 4.7953x over previous
//
#include <hip/hip_runtime.h>
#include <hip/hip_bf16.h>
#include <math.h>

// GPT-2 forward. B=2,T=1024,C=768,H=12,D=64,L=12,VP=50304.
// GEMMs + attention use f16 MFMA (fp32 accumulate); residual stream stays fp32.
#define BB 2
#define TT 1024
#define CC 768
#define NH 12
#define HD 64
#define NL 12
#define VP 50304
#define MM (BB * TT)   // 2048 rows

typedef _Float16 half8 __attribute__((ext_vector_type(8)));
typedef float floatx4 __attribute__((ext_vector_type(4)));

__device__ __forceinline__ float gelu_tanh(float x) {
    const float k = 0.7978845608028654f;  // sqrt(2/pi)
    float x3 = x * x * x;
    return 0.5f * x * (1.0f + tanhf(k * (x + 0.044715f * x3)));
}

__device__ __forceinline__ half8 cvt8(float4 a, float4 b) {
    half8 h;
    h[0] = (_Float16)a.x; h[1] = (_Float16)a.y;
    h[2] = (_Float16)a.z; h[3] = (_Float16)a.w;
    h[4] = (_Float16)b.x; h[5] = (_Float16)b.y;
    h[6] = (_Float16)b.z; h[7] = (_Float16)b.w;
    return h;
}

// ---------------- embedding: x[b,t,c] = wte[idx[b,t],c] + wpe[t,c] ----------
__global__ void embed_kernel(const int* __restrict__ idx,
                             const float* __restrict__ wte,
                             const float* __restrict__ wpe,
                             float* __restrict__ x, int n) {
    int i = blockIdx.x * blockDim.x + threadIdx.x;
    if (i >= n) return;
    int c = i % CC;
    int bt = i / CC;
    int t = bt % TT;
    x[i] = wte[(size_t)idx[bt] * CC + c] + wpe[(size_t)t * CC + c];
}

// ---------------- layernorm: one 256-thread block per row (C=768=3*256) ----
__launch_bounds__(256)
__global__ void ln_kernel(const float* __restrict__ x,
                          const float* __restrict__ w,
                          const float* __restrict__ b,
                          float* __restrict__ out) {
    int row = blockIdx.x;
    int tid = threadIdx.x;
    const float* xr = x + (size_t)row * CC;
    __shared__ float red[256];
    float v0 = xr[tid], v1 = xr[tid + 256], v2 = xr[tid + 512];
    red[tid] = v0 + v1 + v2;
    __syncthreads();
    for (int s = 128; s > 0; s >>= 1) {
        if (tid < s) red[tid] += red[tid + s];
        __syncthreads();
    }
    float mu = red[0] * (1.0f / CC);
    __syncthreads();
    float d0 = v0 - mu, d1 = v1 - mu, d2 = v2 - mu;
    red[tid] = d0 * d0 + d1 * d1 + d2 * d2;
    __syncthreads();
    for (int s = 128; s > 0; s >>= 1) {
        if (tid < s) red[tid] += red[tid + s];
        __syncthreads();
    }
    float rstd = rsqrtf(red[0] * (1.0f / CC) + 1e-5f);
    float* outr = out + (size_t)row * CC;
    outr[tid]       = d0 * rstd * w[tid]       + b[tid];
    outr[tid + 256] = d1 * rstd * w[tid + 256] + b[tid + 256];
    outr[tid + 512] = d2 * rstd * w[tid + 512] + b[tid + 512];
}

// ---------------- MFMA GEMM: out = (res?) + bias + A @ W^T ------------------
// A: (M,K) fp32 row-major. W: (N,K) fp32 row-major. Converted to f16 while
// staging into LDS; v_mfma_f32_16x16x32_f16, fp32 accumulation.
// Block: 256 thr (4 waves, 2x2), tile 128x128, BK=32, 64x64 per wave.
// M,N multiples of 128; K multiple of 32 (all shapes here satisfy this).
// LDS chunk XOR swizzle (chunk ^= (row>>1)&3) balances both the staging
// ds_write_b128s and the fragment ds_read_b128s across all 8 bank-quads.
template <bool GELU, bool RES>
__launch_bounds__(256)
__global__ void gemm_kernel(const float* __restrict__ A,
                            const float* __restrict__ W,
                            const float* __restrict__ bias,
                            const float* __restrict__ res,
                            float* __restrict__ out,
                            int M, int N, int K) {
    __shared__ __align__(16) _Float16 As[128 * 32];
    __shared__ __align__(16) _Float16 Ws[128 * 32];
    half8* As8 = (half8*)As;
    half8* Ws8 = (half8*)Ws;

    const int tid  = threadIdx.x;
    const int lane = tid & 63;
    const int wid  = tid >> 6;
    const int wr   = (wid >> 1) * 64;   // wave row offset in tile
    const int wc   = (wid & 1) * 64;    // wave col offset in tile
    const int g    = lane >> 4;         // k-chunk group 0..3
    const int c16  = lane & 15;
    const int bm   = blockIdx.y * 128, bn = blockIdx.x * 128;

    // staging: thread t stages row (t>>1) of A and W, k-half (t&1)*16
    const int sr  = tid >> 1;           // 0..127
    const int sc0 = (tid & 1) * 2;      // first of 2 chunks (chunk = 8 f16)
    const int sz  = (sr >> 1) & 3;      // xor key for this row
    const float* Ap = A + (size_t)(bm + sr) * K + sc0 * 8;
    const float* Wp = W + (size_t)(bn + sr) * K + sc0 * 8;

    floatx4 acc[4][4] = {};

    for (int k0 = 0; k0 < K; k0 += 32) {
        float4 a0 = *(const float4*)(Ap + k0);
        float4 a1 = *(const float4*)(Ap + k0 + 4);
        float4 a2 = *(const float4*)(Ap + k0 + 8);
        float4 a3 = *(const float4*)(Ap + k0 + 12);
        float4 w0 = *(const float4*)(Wp + k0);
        float4 w1 = *(const float4*)(Wp + k0 + 4);
        float4 w2 = *(const float4*)(Wp + k0 + 8);
        float4 w3 = *(const float4*)(Wp + k0 + 12);
        __syncthreads();   // previous iter's fragment reads complete
        As8[sr * 4 + (sc0 ^ sz)]       = cvt8(a0, a1);
        As8[sr * 4 + ((sc0 + 1) ^ sz)] = cvt8(a2, a3);
        Ws8[sr * 4 + (sc0 ^ sz)]       = cvt8(w0, w1);
        Ws8[sr * 4 + ((sc0 + 1) ^ sz)] = cvt8(w2, w3);
        __syncthreads();
        half8 af[4], bf[4];
#pragma unroll
        for (int i = 0; i < 4; ++i) {
            int ra = wr + i * 16 + c16;
            af[i] = As8[ra * 4 + (g ^ ((ra >> 1) & 3))];
            int rb = wc + i * 16 + c16;
            bf[i] = Ws8[rb * 4 + (g ^ ((rb >> 1) & 3))];
        }
#pragma unroll
        for (int i = 0; i < 4; ++i)
#pragma unroll
            for (int j = 0; j < 4; ++j)
                acc[i][j] = __builtin_amdgcn_mfma_f32_16x16x32_f16(
                    af[i], bf[j], acc[i][j], 0, 0, 0);
    }

    // epilogue: C/D layout row=(lane>>4)*4+r, col=lane&15 (m89-verified)
#pragma unroll
    for (int i = 0; i < 4; ++i) {
#pragma unroll
        for (int j = 0; j < 4; ++j) {
#pragma unroll
            for (int r = 0; r < 4; ++r) {
                int row = bm + wr + i * 16 + g * 4 + r;
                int col = bn + wc + j * 16 + c16;
                float v = acc[i][j][r];
                if (bias) v += bias[col];
                if (GELU) v = gelu_tanh(v);
                if (RES) v += res[(size_t)row * N + col];
                out[(size_t)row * N + col] = v;
            }
        }
    }
}

// ---------------- flash attention, MFMA f16 ---------------------------------
// Block = 256 thr (4 waves) handles (b, h, 64-row q-tile). Wave w owns q rows
// [qt*64+w*16, +16). K staged row-major f16 in LDS; V staged TRANSPOSED
// (Vt[d][k]) so the PV B-fragment is a contiguous half8 read. Online softmax
// on the S-fragment layout: lane holds S[q=4g+r][k=16j+c]; row reductions are
// 16-lane shfl_xor butterflies. P goes through wave-private LDS (no barrier).
__launch_bounds__(256)
__global__ void attn_kernel(const float* __restrict__ qkv,
                            float* __restrict__ y) {
    __shared__ __align__(16) _Float16 Ks[64][80];       // [k][d], pad 80
    __shared__ __align__(16) _Float16 Vt[64][80];       // [d][k], pad 80
    __shared__ __align__(16) _Float16 Pl[4][16][80];    // per-wave P tile

    const int tid  = threadIdx.x;
    const int lane = tid & 63;
    const int w    = tid >> 6;
    const int g    = lane >> 4;
    const int c    = lane & 15;

    const int qt = blockIdx.x & 15;
    const int h  = (blockIdx.x >> 4) % NH;
    const int b  = blockIdx.x / (16 * NH);

    const size_t rstride = 3 * CC;
    const float* qbase = qkv + (size_t)(b * TT) * rstride + h * HD;
    const float* kbase = qbase + CC;
    const float* vbase = qbase + 2 * CC;

    // Q fragments (hoisted): row c of wave's 16-q block, d = 32*ks + 8*g + jj
    half8 qf[2];
    {
        const float* qrow = qbase + (size_t)(qt * 64 + w * 16 + c) * rstride;
#pragma unroll
        for (int ks = 0; ks < 2; ++ks) {
            float4 x0 = *(const float4*)(qrow + 32 * ks + 8 * g);
            float4 x1 = *(const float4*)(qrow + 32 * ks + 8 * g + 4);
            half8 hv;
            hv[0] = (_Float16)(x0.x * 0.125f); hv[1] = (_Float16)(x0.y * 0.125f);
            hv[2] = (_Float16)(x0.z * 0.125f); hv[3] = (_Float16)(x0.w * 0.125f);
            hv[4] = (_Float16)(x1.x * 0.125f); hv[5] = (_Float16)(x1.y * 0.125f);
            hv[6] = (_Float16)(x1.z * 0.125f); hv[7] = (_Float16)(x1.w * 0.125f);
            qf[ks] = hv;
        }
    }

    float mrow[4] = {-1e30f, -1e30f, -1e30f, -1e30f};
    float lrow[4] = {0.0f, 0.0f, 0.0f, 0.0f};
    floatx4 accO[4] = {};

    const int srow = tid >> 2;          // 0..63 staged k-row
    const int scol = (tid & 3) * 16;    // 16-wide d-slab

    for (int kt = 0; kt <= qt; ++kt) {
        __syncthreads();   // previous iter's Ks/Vt reads complete
        {
            const float* kr = kbase + (size_t)(kt * 64 + srow) * rstride + scol;
            float4 k0 = *(const float4*)(kr);
            float4 k1 = *(const float4*)(kr + 4);
            float4 k2 = *(const float4*)(kr + 8);
            float4 k3 = *(const float4*)(kr + 12);
            *(half8*)&Ks[srow][scol]     = cvt8(k0, k1);
            *(half8*)&Ks[srow][scol + 8] = cvt8(k2, k3);
            const float* vr = vbase + (size_t)(kt * 64 + srow) * rstride + scol;
#pragma unroll
            for (int q4 = 0; q4 < 4; ++q4) {
                float4 v = *(const float4*)(vr + 4 * q4);
                Vt[scol + 4 * q4 + 0][srow] = (_Float16)v.x;
                Vt[scol + 4 * q4 + 1][srow] = (_Float16)v.y;
                Vt[scol + 4 * q4 + 2][srow] = (_Float16)v.z;
                Vt[scol + 4 * q4 + 3][srow] = (_Float16)v.w;
            }
        }
        __syncthreads();

        // S = Q K^T (scaled): lane holds S[4g+r][16j+c], r,j in 0..3
        floatx4 sf[4] = {};
#pragma unroll
        for (int ks = 0; ks < 2; ++ks) {
#pragma unroll
            for (int j = 0; j < 4; ++j) {
                half8 kf = *(const half8*)&Ks[16 * j + c][32 * ks + 8 * g];
                sf[j] = __builtin_amdgcn_mfma_f32_16x16x32_f16(
                    qf[ks], kf, sf[j], 0, 0, 0);
            }
        }
        if (kt == qt) {  // causal mask on the diagonal tile
#pragma unroll
            for (int j = 0; j < 4; ++j)
#pragma unroll
                for (int r = 0; r < 4; ++r)
                    if (16 * j + c > w * 16 + 4 * g + r) sf[j][r] = -1e30f;
        }

        // row max (over 64 k): in-lane over j, butterfly over the 16 cols
        float rm[4];
#pragma unroll
        for (int r = 0; r < 4; ++r)
            rm[r] = fmaxf(fmaxf(sf[0][r], sf[1][r]), fmaxf(sf[2][r], sf[3][r]));
#pragma unroll
        for (int off = 1; off < 16; off <<= 1)
#pragma unroll
            for (int r = 0; r < 4; ++r)
                rm[r] = fmaxf(rm[r], __shfl_xor(rm[r], off));

        float corr[4];
#pragma unroll
        for (int r = 0; r < 4; ++r) {
            float mn = fmaxf(mrow[r], rm[r]);
            corr[r] = __expf(mrow[r] - mn);   // 0 on first tile
            mrow[r] = mn;
        }
        float ps[4][4];  // [j][r]
#pragma unroll
        for (int j = 0; j < 4; ++j)
#pragma unroll
            for (int r = 0; r < 4; ++r)
                ps[j][r] = __expf(sf[j][r] - mrow[r]);
        float rs[4];
#pragma unroll
        for (int r = 0; r < 4; ++r)
            rs[r] = (ps[0][r] + ps[1][r]) + (ps[2][r] + ps[3][r]);
#pragma unroll
        for (int off = 1; off < 16; off <<= 1)
#pragma unroll
            for (int r = 0; r < 4; ++r)
                rs[r] += __shfl_xor(rs[r], off);
#pragma unroll
        for (int r = 0; r < 4; ++r)
            lrow[r] = lrow[r] * corr[r] + rs[r];
#pragma unroll
        for (int jd = 0; jd < 4; ++jd)
#pragma unroll
            for (int r = 0; r < 4; ++r)
                accO[jd][r] *= corr[r];

        // P -> f16 via wave-private LDS (in-order LDS within a wave; no barrier)
#pragma unroll
        for (int j = 0; j < 4; ++j)
#pragma unroll
            for (int r = 0; r < 4; ++r)
                Pl[w][4 * g + r][16 * j + c] = (_Float16)ps[j][r];

        // O += P V : A-frag = P rows, B-frag = Vt rows (contiguous half8)
#pragma unroll
        for (int ks = 0; ks < 2; ++ks) {
            half8 pa = *(const half8*)&Pl[w][c][32 * ks + 8 * g];
#pragma unroll
            for (int jd = 0; jd < 4; ++jd) {
                half8 vb = *(const half8*)&Vt[16 * jd + c][32 * ks + 8 * g];
                accO[jd] = __builtin_amdgcn_mfma_f32_16x16x32_f16(
                    pa, vb, accO[jd], 0, 0, 0);
            }
        }
    }

    // epilogue: y[b, q, h*64 + d] = O / l
#pragma unroll
    for (int jd = 0; jd < 4; ++jd)
#pragma unroll
        for (int r = 0; r < 4; ++r) {
            int q = qt * 64 + w * 16 + 4 * g + r;
            y[((size_t)(b * TT + q)) * CC + h * HD + 16 * jd + c] =
                accO[jd][r] / lrow[r];
        }
}

extern "C" void kernel_launch(void* const* d_in, const int* in_sizes, int n_in,
                              void* d_out, int out_size, void* d_ws, size_t ws_size,
                              hipStream_t stream) {
    const int*   idx     = (const int*)d_in[0];
    const float* wte     = (const float*)d_in[1];
    const float* wpe     = (const float*)d_in[2];
    const float* ln1w    = (const float*)d_in[3];
    const float* ln1b    = (const float*)d_in[4];
    const float* qkvw    = (const float*)d_in[5];
    const float* qkvb    = (const float*)d_in[6];
    const float* projw   = (const float*)d_in[7];
    const float* projb   = (const float*)d_in[8];
    const float* ln2w    = (const float*)d_in[9];
    const float* ln2b    = (const float*)d_in[10];
    const float* fcw     = (const float*)d_in[11];
    const float* fcb     = (const float*)d_in[12];
    const float* fcprojw = (const float*)d_in[13];
    const float* fcprojb = (const float*)d_in[14];
    const float* lnfw    = (const float*)d_in[15];
    const float* lnfb    = (const float*)d_in[16];
    float* logits = (float*)d_out;

    // workspace layout (floats)
    float* ws = (float*)d_ws;
    const size_t xn = (size_t)MM * CC;          // 1,572,864
    float* x   = ws;                            // residual stream
    float* h   = x + xn;                        // LN output
    float* y   = h + xn;                        // attention output
    float* big = y + xn;                        // qkv (2048x2304) / fc act (2048x3072)
    float* qkv = big;
    float* hfc = big;

    const int M = MM;
    dim3 tb(256);

    // embedding
    {
        int n = (int)xn;
        embed_kernel<<<(n + 255) / 256, tb, 0, stream>>>(idx, wte, wpe, x, n);
    }

    for (int l = 0; l < NL; ++l) {
        // LN1
        ln_kernel<<<M, tb, 0, stream>>>(x, ln1w + l * CC, ln1b + l * CC, h);
        // qkv = h @ qkvw^T + qkvb   (N = 2304)
        gemm_kernel<false, false><<<dim3(2304 / 128, M / 128), tb, 0, stream>>>(
            h, qkvw + (size_t)l * 3 * CC * CC, qkvb + (size_t)l * 3 * CC,
            nullptr, qkv, M, 3 * CC, CC);
        // attention (flash, q-tiles of 64)
        attn_kernel<<<dim3(BB * NH * (TT / 64)), tb, 0, stream>>>(qkv, y);
        // x = x + y @ projw^T + projb  (N = 768)
        gemm_kernel<false, true><<<dim3(CC / 128, M / 128), tb, 0, stream>>>(
            y, projw + (size_t)l * CC * CC, projb + (size_t)l * CC,
            x, x, M, CC, CC);
        // LN2
        ln_kernel<<<M, tb, 0, stream>>>(x, ln2w + l * CC, ln2b + l * CC, h);
        // hfc = gelu(h @ fcw^T + fcb)  (N = 3072)
        gemm_kernel<true, false><<<dim3(4 * CC / 128, M / 128), tb, 0, stream>>>(
            h, fcw + (size_t)l * 4 * CC * CC, fcb + (size_t)l * 4 * CC,
            nullptr, hfc, M, 4 * CC, CC);
        // x = x + hfc @ fcprojw^T + fcprojb  (K = 3072)
        gemm_kernel<false, true><<<dim3(CC / 128, M / 128), tb, 0, stream>>>(
            hfc, fcprojw + (size_t)l * CC * 4 * CC, fcprojb + (size_t)l * CC,
            x, x, M, CC, 4 * CC);
    }

    // final LN
    ln_kernel<<<M, tb, 0, stream>>>(x, lnfw, lnfb, h);
    // logits = h @ wte^T  (N = 50304, no bias)
    gemm_kernel<false, false><<<dim3(VP / 128, M / 128), tb, 0, stream>>>(
        h, wte, nullptr, nullptr, logits, M, VP, CC);
}

// Round 2
// 4199.326 us; speedup vs baseline: 6.0964x; 1.2713x over previous
//
#include <hip/hip_runtime.h>
#include <hip/hip_bf16.h>
#include <math.h>

// GPT-2 forward. B=2,T=1024,C=768,H=12,D=64,L=12,VP=50304.
// GEMMs + attention use f16 MFMA (fp32 accumulate); residual stream stays fp32.
#define BB 2
#define TT 1024
#define CC 768
#define NH 12
#define HD 64
#define NL 12
#define VP 50304
#define MM (BB * TT)   // 2048 rows

typedef _Float16 half8 __attribute__((ext_vector_type(8)));
typedef float floatx4 __attribute__((ext_vector_type(4)));

__device__ __forceinline__ float gelu_tanh(float x) {
    const float k = 0.7978845608028654f;  // sqrt(2/pi)
    float x3 = x * x * x;
    return 0.5f * x * (1.0f + tanhf(k * (x + 0.044715f * x3)));
}

__device__ __forceinline__ half8 cvt8(float4 a, float4 b) {
    half8 h;
    h[0] = (_Float16)a.x; h[1] = (_Float16)a.y;
    h[2] = (_Float16)a.z; h[3] = (_Float16)a.w;
    h[4] = (_Float16)b.x; h[5] = (_Float16)b.y;
    h[6] = (_Float16)b.z; h[7] = (_Float16)b.w;
    return h;
}

// ---------------- embedding: x[b,t,c] = wte[idx[b,t],c] + wpe[t,c] ----------
__global__ void embed_kernel(const int* __restrict__ idx,
                             const float* __restrict__ wte,
                             const float* __restrict__ wpe,
                             float* __restrict__ x, int n) {
    int i = blockIdx.x * blockDim.x + threadIdx.x;
    if (i >= n) return;
    int c = i % CC;
    int bt = i / CC;
    int t = bt % TT;
    x[i] = wte[(size_t)idx[bt] * CC + c] + wpe[(size_t)t * CC + c];
}

// ---------------- layernorm: one 256-thread block per row (C=768=3*256) ----
__launch_bounds__(256)
__global__ void ln_kernel(const float* __restrict__ x,
                          const float* __restrict__ w,
                          const float* __restrict__ b,
                          float* __restrict__ out) {
    int row = blockIdx.x;
    int tid = threadIdx.x;
    const float* xr = x + (size_t)row * CC;
    __shared__ float red[256];
    float v0 = xr[tid], v1 = xr[tid + 256], v2 = xr[tid + 512];
    red[tid] = v0 + v1 + v2;
    __syncthreads();
    for (int s = 128; s > 0; s >>= 1) {
        if (tid < s) red[tid] += red[tid + s];
        __syncthreads();
    }
    float mu = red[0] * (1.0f / CC);
    __syncthreads();
    float d0 = v0 - mu, d1 = v1 - mu, d2 = v2 - mu;
    red[tid] = d0 * d0 + d1 * d1 + d2 * d2;
    __syncthreads();
    for (int s = 128; s > 0; s >>= 1) {
        if (tid < s) red[tid] += red[tid + s];
        __syncthreads();
    }
    float rstd = rsqrtf(red[0] * (1.0f / CC) + 1e-5f);
    float* outr = out + (size_t)row * CC;
    outr[tid]       = d0 * rstd * w[tid]       + b[tid];
    outr[tid + 256] = d1 * rstd * w[tid + 256] + b[tid + 256];
    outr[tid + 512] = d2 * rstd * w[tid + 512] + b[tid + 512];
}

// ---------------- MFMA GEMM: out = (res?) + bias + A @ W^T ------------------
// A: (M,K) fp32 row-major. W: (N,K) fp32 row-major. Converted to f16 while
// staging into LDS; v_mfma_f32_16x16x32_f16, fp32 accumulation.
// Block: 256 thr (4 waves, 2x2). Tile BMxBN (128x128 or 64x64), BK=32.
// 1D grid; in-kernel bijective XCD chunk-swizzle (m204) + row-fast ordering:
// consecutive logical blocks share one W panel AND run on one XCD, so each
// W panel is fetched into exactly one L2 (was 8x panel over-fetch).
// LDS chunk XOR swizzle (chunk ^= (row>>1)&3) keeps staging writes and
// fragment ds_read_b128s bank-conflict-free (verified: SQ_LDS_BANK_CONFLICT=0).
template <int BM, int BN, bool GELU, bool RES>
__launch_bounds__(256)
__global__ void gemm_kernel(const float* __restrict__ A,
                            const float* __restrict__ W,
                            const float* __restrict__ bias,
                            const float* __restrict__ res,
                            float* __restrict__ out,
                            int M, int N, int K) {
    __shared__ __align__(16) _Float16 As[BM * 32];
    __shared__ __align__(16) _Float16 Ws[BN * 32];
    half8* As8 = (half8*)As;
    half8* Ws8 = (half8*)Ws;

    constexpr int FI = BM / 32;   // frags per wave, rows
    constexpr int FJ = BN / 32;   // frags per wave, cols

    const int tid  = threadIdx.x;
    const int lane = tid & 63;
    const int wid  = tid >> 6;
    const int wr   = (wid >> 1) * (BM / 2);
    const int wc   = (wid & 1) * (BN / 2);
    const int g    = lane >> 4;         // k-chunk group 0..3
    const int c16  = lane & 15;

    // XCD-aware bijective remap, then row-fast (M-fast) block ordering.
    const int nwg = gridDim.x;
    const int hw  = blockIdx.x;
    const int xcd = hw & 7;
    const int q   = nwg >> 3, r = nwg & 7;
    const int logical =
        (xcd < r ? xcd * (q + 1) : r * (q + 1) + (xcd - r) * q) + (hw >> 3);
    const int mblocks = M / BM;
    const int bm = (logical % mblocks) * BM;
    const int bn = (logical / mblocks) * BN;

    floatx4 acc[FI][FJ] = {};

    if constexpr (BM == 128) {
        // staging: thread t stages row (t>>1), k-half (t&1)*16 (2 chunks)
        const int sr  = tid >> 1;
        const int sc0 = (tid & 1) * 2;
        const int sz  = (sr >> 1) & 3;
        const float* Ap = A + (size_t)(bm + sr) * K + sc0 * 8;
        const float* Wp = W + (size_t)(bn + sr) * K + sc0 * 8;
        for (int k0 = 0; k0 < K; k0 += 32) {
            float4 a0 = *(const float4*)(Ap + k0);
            float4 a1 = *(const float4*)(Ap + k0 + 4);
            float4 a2 = *(const float4*)(Ap + k0 + 8);
            float4 a3 = *(const float4*)(Ap + k0 + 12);
            float4 w0 = *(const float4*)(Wp + k0);
            float4 w1 = *(const float4*)(Wp + k0 + 4);
            float4 w2 = *(const float4*)(Wp + k0 + 8);
            float4 w3 = *(const float4*)(Wp + k0 + 12);
            __syncthreads();   // previous iter's fragment reads complete
            As8[sr * 4 + (sc0 ^ sz)]       = cvt8(a0, a1);
            As8[sr * 4 + ((sc0 + 1) ^ sz)] = cvt8(a2, a3);
            Ws8[sr * 4 + (sc0 ^ sz)]       = cvt8(w0, w1);
            Ws8[sr * 4 + ((sc0 + 1) ^ sz)] = cvt8(w2, w3);
            __syncthreads();
            half8 af[FI], bf[FJ];
#pragma unroll
            for (int i = 0; i < FI; ++i) {
                int ra = wr + i * 16 + c16;
                af[i] = As8[ra * 4 + (g ^ ((ra >> 1) & 3))];
            }
#pragma unroll
            for (int j = 0; j < FJ; ++j) {
                int rb = wc + j * 16 + c16;
                bf[j] = Ws8[rb * 4 + (g ^ ((rb >> 1) & 3))];
            }
#pragma unroll
            for (int i = 0; i < FI; ++i)
#pragma unroll
                for (int j = 0; j < FJ; ++j)
                    acc[i][j] = __builtin_amdgcn_mfma_f32_16x16x32_f16(
                        af[i], bf[j], acc[i][j], 0, 0, 0);
        }
    } else {
        // BM == BN == 64: thread t stages row (t>>2), chunk (t&3)
        const int sr = tid >> 2;
        const int sc = tid & 3;
        const int sz = (sr >> 1) & 3;
        const float* Ap = A + (size_t)(bm + sr) * K + sc * 8;
        const float* Wp = W + (size_t)(bn + sr) * K + sc * 8;
        for (int k0 = 0; k0 < K; k0 += 32) {
            float4 a0 = *(const float4*)(Ap + k0);
            float4 a1 = *(const float4*)(Ap + k0 + 4);
            float4 w0 = *(const float4*)(Wp + k0);
            float4 w1 = *(const float4*)(Wp + k0 + 4);
            __syncthreads();
            As8[sr * 4 + (sc ^ sz)] = cvt8(a0, a1);
            Ws8[sr * 4 + (sc ^ sz)] = cvt8(w0, w1);
            __syncthreads();
            half8 af[FI], bf[FJ];
#pragma unroll
            for (int i = 0; i < FI; ++i) {
                int ra = wr + i * 16 + c16;
                af[i] = As8[ra * 4 + (g ^ ((ra >> 1) & 3))];
            }
#pragma unroll
            for (int j = 0; j < FJ; ++j) {
                int rb = wc + j * 16 + c16;
                bf[j] = Ws8[rb * 4 + (g ^ ((rb >> 1) & 3))];
            }
#pragma unroll
            for (int i = 0; i < FI; ++i)
#pragma unroll
                for (int j = 0; j < FJ; ++j)
                    acc[i][j] = __builtin_amdgcn_mfma_f32_16x16x32_f16(
                        af[i], bf[j], acc[i][j], 0, 0, 0);
        }
    }

    // epilogue: C/D layout row=(lane>>4)*4+r, col=lane&15 (m89-verified)
#pragma unroll
    for (int i = 0; i < FI; ++i) {
#pragma unroll
        for (int j = 0; j < FJ; ++j) {
#pragma unroll
            for (int r = 0; r < 4; ++r) {
                int row = bm + wr + i * 16 + g * 4 + r;
                int col = bn + wc + j * 16 + c16;
                float v = acc[i][j][r];
                if (bias) v += bias[col];
                if (GELU) v = gelu_tanh(v);
                if (RES) v += res[(size_t)row * N + col];
                out[(size_t)row * N + col] = v;
            }
        }
    }
}

// ---------------- flash attention, MFMA f16 ---------------------------------
// Block = 256 thr (4 waves) handles (b, h, 64-row q-tile). Wave w owns q rows
// [qt*64+w*16, +16). K staged row-major f16 in LDS; V staged TRANSPOSED
// (Vt[d][k]) so the PV B-fragment is a contiguous half8 read. Online softmax
// on the S-fragment layout: lane holds S[q=4g+r][k=16j+c]; row reductions are
// 16-lane shfl_xor butterflies. P goes through wave-private LDS (no barrier).
__launch_bounds__(256)
__global__ void attn_kernel(const float* __restrict__ qkv,
                            float* __restrict__ y) {
    __shared__ __align__(16) _Float16 Ks[64][80];       // [k][d], pad 80
    __shared__ __align__(16) _Float16 Vt[64][80];       // [d][k], pad 80
    __shared__ __align__(16) _Float16 Pl[4][16][80];    // per-wave P tile

    const int tid  = threadIdx.x;
    const int lane = tid & 63;
    const int w    = tid >> 6;
    const int g    = lane >> 4;
    const int c    = lane & 15;

    const int qt = blockIdx.x & 15;
    const int h  = (blockIdx.x >> 4) % NH;
    const int b  = blockIdx.x / (16 * NH);

    const size_t rstride = 3 * CC;
    const float* qbase = qkv + (size_t)(b * TT) * rstride + h * HD;
    const float* kbase = qbase + CC;
    const float* vbase = qbase + 2 * CC;

    // Q fragments (hoisted): row c of wave's 16-q block, d = 32*ks + 8*g + jj
    half8 qf[2];
    {
        const float* qrow = qbase + (size_t)(qt * 64 + w * 16 + c) * rstride;
#pragma unroll
        for (int ks = 0; ks < 2; ++ks) {
            float4 x0 = *(const float4*)(qrow + 32 * ks + 8 * g);
            float4 x1 = *(const float4*)(qrow + 32 * ks + 8 * g + 4);
            half8 hv;
            hv[0] = (_Float16)(x0.x * 0.125f); hv[1] = (_Float16)(x0.y * 0.125f);
            hv[2] = (_Float16)(x0.z * 0.125f); hv[3] = (_Float16)(x0.w * 0.125f);
            hv[4] = (_Float16)(x1.x * 0.125f); hv[5] = (_Float16)(x1.y * 0.125f);
            hv[6] = (_Float16)(x1.z * 0.125f); hv[7] = (_Float16)(x1.w * 0.125f);
            qf[ks] = hv;
        }
    }

    float mrow[4] = {-1e30f, -1e30f, -1e30f, -1e30f};
    float lrow[4] = {0.0f, 0.0f, 0.0f, 0.0f};
    floatx4 accO[4] = {};

    const int srow = tid >> 2;          // 0..63 staged k-row
    const int scol = (tid & 3) * 16;    // 16-wide d-slab

    for (int kt = 0; kt <= qt; ++kt) {
        __syncthreads();   // previous iter's Ks/Vt reads complete
        {
            const float* kr = kbase + (size_t)(kt * 64 + srow) * rstride + scol;
            float4 k0 = *(const float4*)(kr);
            float4 k1 = *(const float4*)(kr + 4);
            float4 k2 = *(const float4*)(kr + 8);
            float4 k3 = *(const float4*)(kr + 12);
            *(half8*)&Ks[srow][scol]     = cvt8(k0, k1);
            *(half8*)&Ks[srow][scol + 8] = cvt8(k2, k3);
            const float* vr = vbase + (size_t)(kt * 64 + srow) * rstride + scol;
#pragma unroll
            for (int q4 = 0; q4 < 4; ++q4) {
                float4 v = *(const float4*)(vr + 4 * q4);
                Vt[scol + 4 * q4 + 0][srow] = (_Float16)v.x;
                Vt[scol + 4 * q4 + 1][srow] = (_Float16)v.y;
                Vt[scol + 4 * q4 + 2][srow] = (_Float16)v.z;
                Vt[scol + 4 * q4 + 3][srow] = (_Float16)v.w;
            }
        }
        __syncthreads();

        // S = Q K^T (scaled): lane holds S[4g+r][16j+c], r,j in 0..3
        floatx4 sf[4] = {};
#pragma unroll
        for (int ks = 0; ks < 2; ++ks) {
#pragma unroll
            for (int j = 0; j < 4; ++j) {
                half8 kf = *(const half8*)&Ks[16 * j + c][32 * ks + 8 * g];
                sf[j] = __builtin_amdgcn_mfma_f32_16x16x32_f16(
                    qf[ks], kf, sf[j], 0, 0, 0);
            }
        }
        if (kt == qt) {  // causal mask on the diagonal tile
#pragma unroll
            for (int j = 0; j < 4; ++j)
#pragma unroll
                for (int r = 0; r < 4; ++r)
                    if (16 * j + c > w * 16 + 4 * g + r) sf[j][r] = -1e30f;
        }

        // row max (over 64 k): in-lane over j, butterfly over the 16 cols
        float rm[4];
#pragma unroll
        for (int r = 0; r < 4; ++r)
            rm[r] = fmaxf(fmaxf(sf[0][r], sf[1][r]), fmaxf(sf[2][r], sf[3][r]));
#pragma unroll
        for (int off = 1; off < 16; off <<= 1)
#pragma unroll
            for (int r = 0; r < 4; ++r)
                rm[r] = fmaxf(rm[r], __shfl_xor(rm[r], off));

        float corr[4];
#pragma unroll
        for (int r = 0; r < 4; ++r) {
            float mn = fmaxf(mrow[r], rm[r]);
            corr[r] = __expf(mrow[r] - mn);   // 0 on first tile
            mrow[r] = mn;
        }
        float ps[4][4];  // [j][r]
#pragma unroll
        for (int j = 0; j < 4; ++j)
#pragma unroll
            for (int r = 0; r < 4; ++r)
                ps[j][r] = __expf(sf[j][r] - mrow[r]);
        float rs[4];
#pragma unroll
        for (int r = 0; r < 4; ++r)
            rs[r] = (ps[0][r] + ps[1][r]) + (ps[2][r] + ps[3][r]);
#pragma unroll
        for (int off = 1; off < 16; off <<= 1)
#pragma unroll
            for (int r = 0; r < 4; ++r)
                rs[r] += __shfl_xor(rs[r], off);
#pragma unroll
        for (int r = 0; r < 4; ++r)
            lrow[r] = lrow[r] * corr[r] + rs[r];
#pragma unroll
        for (int jd = 0; jd < 4; ++jd)
#pragma unroll
            for (int r = 0; r < 4; ++r)
                accO[jd][r] *= corr[r];

        // P -> f16 via wave-private LDS (in-order LDS within a wave; no barrier)
#pragma unroll
        for (int j = 0; j < 4; ++j)
#pragma unroll
            for (int r = 0; r < 4; ++r)
                Pl[w][4 * g + r][16 * j + c] = (_Float16)ps[j][r];

        // O += P V : A-frag = P rows, B-frag = Vt rows (contiguous half8)
#pragma unroll
        for (int ks = 0; ks < 2; ++ks) {
            half8 pa = *(const half8*)&Pl[w][c][32 * ks + 8 * g];
#pragma unroll
            for (int jd = 0; jd < 4; ++jd) {
                half8 vb = *(const half8*)&Vt[16 * jd + c][32 * ks + 8 * g];
                accO[jd] = __builtin_amdgcn_mfma_f32_16x16x32_f16(
                    pa, vb, accO[jd], 0, 0, 0);
            }
        }
    }

    // epilogue: y[b, q, h*64 + d] = O / l
#pragma unroll
    for (int jd = 0; jd < 4; ++jd)
#pragma unroll
        for (int r = 0; r < 4; ++r) {
            int q = qt * 64 + w * 16 + 4 * g + r;
            y[((size_t)(b * TT + q)) * CC + h * HD + 16 * jd + c] =
                accO[jd][r] / lrow[r];
        }
}

extern "C" void kernel_launch(void* const* d_in, const int* in_sizes, int n_in,
                              void* d_out, int out_size, void* d_ws, size_t ws_size,
                              hipStream_t stream) {
    const int*   idx     = (const int*)d_in[0];
    const float* wte     = (const float*)d_in[1];
    const float* wpe     = (const float*)d_in[2];
    const float* ln1w    = (const float*)d_in[3];
    const float* ln1b    = (const float*)d_in[4];
    const float* qkvw    = (const float*)d_in[5];
    const float* qkvb    = (const float*)d_in[6];
    const float* projw   = (const float*)d_in[7];
    const float* projb   = (const float*)d_in[8];
    const float* ln2w    = (const float*)d_in[9];
    const float* ln2b    = (const float*)d_in[10];
    const float* fcw     = (const float*)d_in[11];
    const float* fcb     = (const float*)d_in[12];
    const float* fcprojw = (const float*)d_in[13];
    const float* fcprojb = (const float*)d_in[14];
    const float* lnfw    = (const float*)d_in[15];
    const float* lnfb    = (const float*)d_in[16];
    float* logits = (float*)d_out;

    // workspace layout (floats)
    float* ws = (float*)d_ws;
    const size_t xn = (size_t)MM * CC;          // 1,572,864
    float* x   = ws;                            // residual stream
    float* h   = x + xn;                        // LN output
    float* y   = h + xn;                        // attention output
    float* big = y + xn;                        // qkv (2048x2304) / fc act (2048x3072)
    float* qkv = big;
    float* hfc = big;

    const int M = MM;
    dim3 tb(256);

    // embedding
    {
        int n = (int)xn;
        embed_kernel<<<(n + 255) / 256, tb, 0, stream>>>(idx, wte, wpe, x, n);
    }

    const int nb_qkv    = (M / 128) * (3 * CC / 128);  // 16*18  = 288
    const int nb_proj   = (M / 64) * (CC / 64);        // 32*12  = 384
    const int nb_fc     = (M / 128) * (4 * CC / 128);  // 16*24  = 384
    const int nb_fcproj = (M / 64) * (CC / 64);        // 32*12  = 384
    const int nb_head   = (M / 128) * (VP / 128);      // 16*393 = 6288

    for (int l = 0; l < NL; ++l) {
        // LN1
        ln_kernel<<<M, tb, 0, stream>>>(x, ln1w + l * CC, ln1b + l * CC, h);
        // qkv = h @ qkvw^T + qkvb   (N = 2304)
        gemm_kernel<128, 128, false, false><<<dim3(nb_qkv), tb, 0, stream>>>(
            h, qkvw + (size_t)l * 3 * CC * CC, qkvb + (size_t)l * 3 * CC,
            nullptr, qkv, M, 3 * CC, CC);
        // attention (flash, q-tiles of 64)
        attn_kernel<<<dim3(BB * NH * (TT / 64)), tb, 0, stream>>>(qkv, y);
        // x = x + y @ projw^T + projb  (N = 768)
        gemm_kernel<64, 64, false, true><<<dim3(nb_proj), tb, 0, stream>>>(
            y, projw + (size_t)l * CC * CC, projb + (size_t)l * CC,
            x, x, M, CC, CC);
        // LN2
        ln_kernel<<<M, tb, 0, stream>>>(x, ln2w + l * CC, ln2b + l * CC, h);
        // hfc = gelu(h @ fcw^T + fcb)  (N = 3072)
        gemm_kernel<128, 128, true, false><<<dim3(nb_fc), tb, 0, stream>>>(
            h, fcw + (size_t)l * 4 * CC * CC, fcb + (size_t)l * 4 * CC,
            nullptr, hfc, M, 4 * CC, CC);
        // x = x + hfc @ fcprojw^T + fcprojb  (K = 3072)
        gemm_kernel<64, 64, false, true><<<dim3(nb_fcproj), tb, 0, stream>>>(
            hfc, fcprojw + (size_t)l * CC * 4 * CC, fcprojb + (size_t)l * CC,
            x, x, M, CC, 4 * CC);
    }

    // final LN
    ln_kernel<<<M, tb, 0, stream>>>(x, lnfw, lnfb, h);
    // logits = h @ wte^T  (N = 50304, no bias)
    gemm_kernel<128, 128, false, false><<<dim3(nb_head), tb, 0, stream>>>(
        h, wte, nullptr, nullptr, logits, M, VP, CC);
}

// Round 3
// 3872.208 us; speedup vs baseline: 6.6114x; 1.0845x over previous
//
#include <hip/hip_runtime.h>
#include <hip/hip_bf16.h>
#include <math.h>

// GPT-2 forward. B=2,T=1024,C=768,H=12,D=64,L=12,VP=50304.
// GEMMs + attention use f16 MFMA (fp32 accumulate); residual stream stays fp32.
// R3: double-buffered LDS (1 barrier/K-step, prefetch overlapped with MFMA),
//     NT stores for logits, exp-based GELU.
#define BB 2
#define TT 1024
#define CC 768
#define NH 12
#define HD 64
#define NL 12
#define VP 50304
#define MM (BB * TT)   // 2048 rows

typedef _Float16 half8 __attribute__((ext_vector_type(8)));
typedef float floatx4 __attribute__((ext_vector_type(4)));

__device__ __forceinline__ float gelu_tanh(float x) {
    const float k = 0.7978845608028654f;  // sqrt(2/pi)
    float u = k * x * (1.0f + 0.044715f * x * x);
    // tanh(u) = 1 - 2/(exp(2u)+1); handles +-inf correctly
    float e = __expf(2.0f * u);
    float t = 1.0f - 2.0f / (e + 1.0f);
    return 0.5f * x * (1.0f + t);
}

__device__ __forceinline__ half8 cvt8(float4 a, float4 b) {
    half8 h;
    h[0] = (_Float16)a.x; h[1] = (_Float16)a.y;
    h[2] = (_Float16)a.z; h[3] = (_Float16)a.w;
    h[4] = (_Float16)b.x; h[5] = (_Float16)b.y;
    h[6] = (_Float16)b.z; h[7] = (_Float16)b.w;
    return h;
}

// ---------------- embedding: x[b,t,c] = wte[idx[b,t],c] + wpe[t,c] ----------
__global__ void embed_kernel(const int* __restrict__ idx,
                             const float* __restrict__ wte,
                             const float* __restrict__ wpe,
                             float* __restrict__ x, int n) {
    int i = blockIdx.x * blockDim.x + threadIdx.x;
    if (i >= n) return;
    int c = i % CC;
    int bt = i / CC;
    int t = bt % TT;
    x[i] = wte[(size_t)idx[bt] * CC + c] + wpe[(size_t)t * CC + c];
}

// ---------------- layernorm: one 256-thread block per row (C=768=3*256) ----
__launch_bounds__(256)
__global__ void ln_kernel(const float* __restrict__ x,
                          const float* __restrict__ w,
                          const float* __restrict__ b,
                          float* __restrict__ out) {
    int row = blockIdx.x;
    int tid = threadIdx.x;
    const float* xr = x + (size_t)row * CC;
    __shared__ float red[256];
    float v0 = xr[tid], v1 = xr[tid + 256], v2 = xr[tid + 512];
    red[tid] = v0 + v1 + v2;
    __syncthreads();
    for (int s = 128; s > 0; s >>= 1) {
        if (tid < s) red[tid] += red[tid + s];
        __syncthreads();
    }
    float mu = red[0] * (1.0f / CC);
    __syncthreads();
    float d0 = v0 - mu, d1 = v1 - mu, d2 = v2 - mu;
    red[tid] = d0 * d0 + d1 * d1 + d2 * d2;
    __syncthreads();
    for (int s = 128; s > 0; s >>= 1) {
        if (tid < s) red[tid] += red[tid + s];
        __syncthreads();
    }
    float rstd = rsqrtf(red[0] * (1.0f / CC) + 1e-5f);
    float* outr = out + (size_t)row * CC;
    outr[tid]       = d0 * rstd * w[tid]       + b[tid];
    outr[tid + 256] = d1 * rstd * w[tid + 256] + b[tid + 256];
    outr[tid + 512] = d2 * rstd * w[tid + 512] + b[tid + 512];
}

// ---------------- MFMA GEMM: out = (res?) + bias + A @ W^T ------------------
// A: (M,K) fp32 row-major. W: (N,K) fp32 row-major. Converted to f16 while
// staging into LDS; v_mfma_f32_16x16x32_f16, fp32 accumulation.
// Block: 256 thr (4 waves, 2x2). Tile BMxBN (128x128 or 64x64), BK=32.
// Double-buffered LDS: one barrier per K-step; tile t+1's global loads issue
// right after the barrier and their latency hides under tile t's MFMAs.
// 1D grid; bijective XCD chunk-swizzle (m204) + row-fast ordering so one W
// panel is fetched into exactly one XCD's L2.
// LDS chunk XOR swizzle (chunk ^= (row>>1)&3) keeps staging writes and
// fragment ds_read_b128s bank-conflict-free (verified: SQ_LDS_BANK_CONFLICT=0).
// NT: non-temporal output stores (lm_head: keep the 402 MB logits stream from
// evicting the wte panels out of L2/L3).
template <int BM, int BN, bool GELU, bool RES, bool NT>
__launch_bounds__(256)
__global__ void gemm_kernel(const float* __restrict__ A,
                            const float* __restrict__ W,
                            const float* __restrict__ bias,
                            const float* __restrict__ res,
                            float* __restrict__ out,
                            int M, int N, int K) {
    __shared__ __align__(16) _Float16 As[2 * BM * 32];
    __shared__ __align__(16) _Float16 Ws[2 * BN * 32];
    half8* As8 = (half8*)As;
    half8* Ws8 = (half8*)Ws;

    constexpr int FI = BM / 32;   // frags per wave, rows
    constexpr int FJ = BN / 32;   // frags per wave, cols

    const int tid  = threadIdx.x;
    const int lane = tid & 63;
    const int wid  = tid >> 6;
    const int wr   = (wid >> 1) * (BM / 2);
    const int wc   = (wid & 1) * (BN / 2);
    const int g    = lane >> 4;         // k-chunk group 0..3
    const int c16  = lane & 15;

    // XCD-aware bijective remap, then row-fast (M-fast) block ordering.
    const int nwg = gridDim.x;
    const int hw  = blockIdx.x;
    const int xcd = hw & 7;
    const int q   = nwg >> 3, r = nwg & 7;
    const int logical =
        (xcd < r ? xcd * (q + 1) : r * (q + 1) + (xcd - r) * q) + (hw >> 3);
    const int mblocks = M / BM;
    const int bm = (logical % mblocks) * BM;
    const int bn = (logical / mblocks) * BN;

    floatx4 acc[FI][FJ] = {};

    if constexpr (BM == 128) {
        // staging: thread t stages row (t>>1), k-half (t&1)*16 (2 chunks)
        const int sr  = tid >> 1;
        const int sc0 = (tid & 1) * 2;
        const int sz  = (sr >> 1) & 3;
        const float* Ap = A + (size_t)(bm + sr) * K + sc0 * 8;
        const float* Wp = W + (size_t)(bn + sr) * K + sc0 * 8;
        float4 a0 = *(const float4*)(Ap);
        float4 a1 = *(const float4*)(Ap + 4);
        float4 a2 = *(const float4*)(Ap + 8);
        float4 a3 = *(const float4*)(Ap + 12);
        float4 w0 = *(const float4*)(Wp);
        float4 w1 = *(const float4*)(Wp + 4);
        float4 w2 = *(const float4*)(Wp + 8);
        float4 w3 = *(const float4*)(Wp + 12);
        for (int k0 = 0; k0 < K; k0 += 32) {
            half8* Acur = As8 + ((k0 >> 5) & 1) * (BM * 4);
            half8* Wcur = Ws8 + ((k0 >> 5) & 1) * (BN * 4);
            Acur[sr * 4 + (sc0 ^ sz)]       = cvt8(a0, a1);
            Acur[sr * 4 + ((sc0 + 1) ^ sz)] = cvt8(a2, a3);
            Wcur[sr * 4 + (sc0 ^ sz)]       = cvt8(w0, w1);
            Wcur[sr * 4 + ((sc0 + 1) ^ sz)] = cvt8(w2, w3);
            __syncthreads();
            if (k0 + 32 < K) {   // prefetch next tile; hides under MFMAs below
                a0 = *(const float4*)(Ap + k0 + 32);
                a1 = *(const float4*)(Ap + k0 + 36);
                a2 = *(const float4*)(Ap + k0 + 40);
                a3 = *(const float4*)(Ap + k0 + 44);
                w0 = *(const float4*)(Wp + k0 + 32);
                w1 = *(const float4*)(Wp + k0 + 36);
                w2 = *(const float4*)(Wp + k0 + 40);
                w3 = *(const float4*)(Wp + k0 + 44);
            }
            half8 af[FI], bf[FJ];
#pragma unroll
            for (int i = 0; i < FI; ++i) {
                int ra = wr + i * 16 + c16;
                af[i] = Acur[ra * 4 + (g ^ ((ra >> 1) & 3))];
            }
#pragma unroll
            for (int j = 0; j < FJ; ++j) {
                int rb = wc + j * 16 + c16;
                bf[j] = Wcur[rb * 4 + (g ^ ((rb >> 1) & 3))];
            }
#pragma unroll
            for (int i = 0; i < FI; ++i)
#pragma unroll
                for (int j = 0; j < FJ; ++j)
                    acc[i][j] = __builtin_amdgcn_mfma_f32_16x16x32_f16(
                        af[i], bf[j], acc[i][j], 0, 0, 0);
        }
    } else {
        // BM == BN == 64: thread t stages row (t>>2), chunk (t&3)
        const int sr = tid >> 2;
        const int sc = tid & 3;
        const int sz = (sr >> 1) & 3;
        const float* Ap = A + (size_t)(bm + sr) * K + sc * 8;
        const float* Wp = W + (size_t)(bn + sr) * K + sc * 8;
        float4 a0 = *(const float4*)(Ap);
        float4 a1 = *(const float4*)(Ap + 4);
        float4 w0 = *(const float4*)(Wp);
        float4 w1 = *(const float4*)(Wp + 4);
        for (int k0 = 0; k0 < K; k0 += 32) {
            half8* Acur = As8 + ((k0 >> 5) & 1) * (BM * 4);
            half8* Wcur = Ws8 + ((k0 >> 5) & 1) * (BN * 4);
            Acur[sr * 4 + (sc ^ sz)] = cvt8(a0, a1);
            Wcur[sr * 4 + (sc ^ sz)] = cvt8(w0, w1);
            __syncthreads();
            if (k0 + 32 < K) {
                a0 = *(const float4*)(Ap + k0 + 32);
                a1 = *(const float4*)(Ap + k0 + 36);
                w0 = *(const float4*)(Wp + k0 + 32);
                w1 = *(const float4*)(Wp + k0 + 36);
            }
            half8 af[FI], bf[FJ];
#pragma unroll
            for (int i = 0; i < FI; ++i) {
                int ra = wr + i * 16 + c16;
                af[i] = Acur[ra * 4 + (g ^ ((ra >> 1) & 3))];
            }
#pragma unroll
            for (int j = 0; j < FJ; ++j) {
                int rb = wc + j * 16 + c16;
                bf[j] = Wcur[rb * 4 + (g ^ ((rb >> 1) & 3))];
            }
#pragma unroll
            for (int i = 0; i < FI; ++i)
#pragma unroll
                for (int j = 0; j < FJ; ++j)
                    acc[i][j] = __builtin_amdgcn_mfma_f32_16x16x32_f16(
                        af[i], bf[j], acc[i][j], 0, 0, 0);
        }
    }

    // epilogue: C/D layout row=(lane>>4)*4+r, col=lane&15 (m89-verified)
#pragma unroll
    for (int i = 0; i < FI; ++i) {
#pragma unroll
        for (int j = 0; j < FJ; ++j) {
#pragma unroll
            for (int r = 0; r < 4; ++r) {
                int row = bm + wr + i * 16 + g * 4 + r;
                int col = bn + wc + j * 16 + c16;
                float v = acc[i][j][r];
                if (bias) v += bias[col];
                if (GELU) v = gelu_tanh(v);
                if (RES) v += res[(size_t)row * N + col];
                if (NT)
                    __builtin_nontemporal_store(v, &out[(size_t)row * N + col]);
                else
                    out[(size_t)row * N + col] = v;
            }
        }
    }
}

// ---------------- flash attention, MFMA f16 ---------------------------------
// Block = 256 thr (4 waves) handles (b, h, 64-row q-tile). Wave w owns q rows
// [qt*64+w*16, +16). K staged row-major f16 in LDS; V staged TRANSPOSED
// (Vt[d][k]) so the PV B-fragment is a contiguous half8 read. K/V double-
// buffered: one barrier per tile, next tile's global loads issued right after
// the barrier (latency hides under S/softmax/PV). Online softmax on the
// S-fragment layout: lane holds S[q=4g+r][k=16j+c]; row reductions are 16-lane
// shfl_xor butterflies. P goes through wave-private LDS (no barrier).
__launch_bounds__(256)
__global__ void attn_kernel(const float* __restrict__ qkv,
                            float* __restrict__ y) {
    __shared__ __align__(16) _Float16 Ks[2][64][80];    // [k][d], pad 80
    __shared__ __align__(16) _Float16 Vt[2][64][80];    // [d][k], pad 80
    __shared__ __align__(16) _Float16 Pl[4][16][80];    // per-wave P tile

    const int tid  = threadIdx.x;
    const int lane = tid & 63;
    const int w    = tid >> 6;
    const int g    = lane >> 4;
    const int c    = lane & 15;

    const int qt = blockIdx.x & 15;
    const int h  = (blockIdx.x >> 4) % NH;
    const int b  = blockIdx.x / (16 * NH);

    const size_t rstride = 3 * CC;
    const float* qbase = qkv + (size_t)(b * TT) * rstride + h * HD;
    const float* kbase = qbase + CC;
    const float* vbase = qbase + 2 * CC;

    // Q fragments (hoisted): row c of wave's 16-q block, d = 32*ks + 8*g + jj
    half8 qf[2];
    {
        const float* qrow = qbase + (size_t)(qt * 64 + w * 16 + c) * rstride;
#pragma unroll
        for (int ks = 0; ks < 2; ++ks) {
            float4 x0 = *(const float4*)(qrow + 32 * ks + 8 * g);
            float4 x1 = *(const float4*)(qrow + 32 * ks + 8 * g + 4);
            half8 hv;
            hv[0] = (_Float16)(x0.x * 0.125f); hv[1] = (_Float16)(x0.y * 0.125f);
            hv[2] = (_Float16)(x0.z * 0.125f); hv[3] = (_Float16)(x0.w * 0.125f);
            hv[4] = (_Float16)(x1.x * 0.125f); hv[5] = (_Float16)(x1.y * 0.125f);
            hv[6] = (_Float16)(x1.z * 0.125f); hv[7] = (_Float16)(x1.w * 0.125f);
            qf[ks] = hv;
        }
    }

    float mrow[4] = {-1e30f, -1e30f, -1e30f, -1e30f};
    float lrow[4] = {0.0f, 0.0f, 0.0f, 0.0f};
    floatx4 accO[4] = {};

    const int srow = tid >> 2;          // 0..63 staged k-row
    const int scol = (tid & 3) * 16;    // 16-wide d-slab

    // prefetch kt=0 K/V tile into registers
    float4 kA, kB, kC, kD, vA, vB, vC, vD;
    {
        const float* kr = kbase + (size_t)srow * rstride + scol;
        kA = *(const float4*)(kr);
        kB = *(const float4*)(kr + 4);
        kC = *(const float4*)(kr + 8);
        kD = *(const float4*)(kr + 12);
        const float* vr = vbase + (size_t)srow * rstride + scol;
        vA = *(const float4*)(vr);
        vB = *(const float4*)(vr + 4);
        vC = *(const float4*)(vr + 8);
        vD = *(const float4*)(vr + 12);
    }

    for (int kt = 0; kt <= qt; ++kt) {
        const int cur = kt & 1;
        *(half8*)&Ks[cur][srow][scol]     = cvt8(kA, kB);
        *(half8*)&Ks[cur][srow][scol + 8] = cvt8(kC, kD);
        Vt[cur][scol +  0][srow] = (_Float16)vA.x;
        Vt[cur][scol +  1][srow] = (_Float16)vA.y;
        Vt[cur][scol +  2][srow] = (_Float16)vA.z;
        Vt[cur][scol +  3][srow] = (_Float16)vA.w;
        Vt[cur][scol +  4][srow] = (_Float16)vB.x;
        Vt[cur][scol +  5][srow] = (_Float16)vB.y;
        Vt[cur][scol +  6][srow] = (_Float16)vB.z;
        Vt[cur][scol +  7][srow] = (_Float16)vB.w;
        Vt[cur][scol +  8][srow] = (_Float16)vC.x;
        Vt[cur][scol +  9][srow] = (_Float16)vC.y;
        Vt[cur][scol + 10][srow] = (_Float16)vC.z;
        Vt[cur][scol + 11][srow] = (_Float16)vC.w;
        Vt[cur][scol + 12][srow] = (_Float16)vD.x;
        Vt[cur][scol + 13][srow] = (_Float16)vD.y;
        Vt[cur][scol + 14][srow] = (_Float16)vD.z;
        Vt[cur][scol + 15][srow] = (_Float16)vD.w;
        __syncthreads();
        if (kt < qt) {   // prefetch next tile; hides under compute below
            const float* kr = kbase + (size_t)((kt + 1) * 64 + srow) * rstride + scol;
            kA = *(const float4*)(kr);
            kB = *(const float4*)(kr + 4);
            kC = *(const float4*)(kr + 8);
            kD = *(const float4*)(kr + 12);
            const float* vr = vbase + (size_t)((kt + 1) * 64 + srow) * rstride + scol;
            vA = *(const float4*)(vr);
            vB = *(const float4*)(vr + 4);
            vC = *(const float4*)(vr + 8);
            vD = *(const float4*)(vr + 12);
        }

        // S = Q K^T (scaled): lane holds S[4g+r][16j+c], r,j in 0..3
        floatx4 sf[4] = {};
#pragma unroll
        for (int ks = 0; ks < 2; ++ks) {
#pragma unroll
            for (int j = 0; j < 4; ++j) {
                half8 kf = *(const half8*)&Ks[cur][16 * j + c][32 * ks + 8 * g];
                sf[j] = __builtin_amdgcn_mfma_f32_16x16x32_f16(
                    qf[ks], kf, sf[j], 0, 0, 0);
            }
        }
        if (kt == qt) {  // causal mask on the diagonal tile
#pragma unroll
            for (int j = 0; j < 4; ++j)
#pragma unroll
                for (int r = 0; r < 4; ++r)
                    if (16 * j + c > w * 16 + 4 * g + r) sf[j][r] = -1e30f;
        }

        // row max (over 64 k): in-lane over j, butterfly over the 16 cols
        float rm[4];
#pragma unroll
        for (int r = 0; r < 4; ++r)
            rm[r] = fmaxf(fmaxf(sf[0][r], sf[1][r]), fmaxf(sf[2][r], sf[3][r]));
#pragma unroll
        for (int off = 1; off < 16; off <<= 1)
#pragma unroll
            for (int r = 0; r < 4; ++r)
                rm[r] = fmaxf(rm[r], __shfl_xor(rm[r], off));

        float corr[4];
#pragma unroll
        for (int r = 0; r < 4; ++r) {
            float mn = fmaxf(mrow[r], rm[r]);
            corr[r] = __expf(mrow[r] - mn);   // 0 on first tile
            mrow[r] = mn;
        }
        float ps[4][4];  // [j][r]
#pragma unroll
        for (int j = 0; j < 4; ++j)
#pragma unroll
            for (int r = 0; r < 4; ++r)
                ps[j][r] = __expf(sf[j][r] - mrow[r]);
        float rs[4];
#pragma unroll
        for (int r = 0; r < 4; ++r)
            rs[r] = (ps[0][r] + ps[1][r]) + (ps[2][r] + ps[3][r]);
#pragma unroll
        for (int off = 1; off < 16; off <<= 1)
#pragma unroll
            for (int r = 0; r < 4; ++r)
                rs[r] += __shfl_xor(rs[r], off);
#pragma unroll
        for (int r = 0; r < 4; ++r)
            lrow[r] = lrow[r] * corr[r] + rs[r];
#pragma unroll
        for (int jd = 0; jd < 4; ++jd)
#pragma unroll
            for (int r = 0; r < 4; ++r)
                accO[jd][r] *= corr[r];

        // P -> f16 via wave-private LDS (in-order LDS within a wave; no barrier)
#pragma unroll
        for (int j = 0; j < 4; ++j)
#pragma unroll
            for (int r = 0; r < 4; ++r)
                Pl[w][4 * g + r][16 * j + c] = (_Float16)ps[j][r];

        // O += P V : A-frag = P rows, B-frag = Vt rows (contiguous half8)
#pragma unroll
        for (int ks = 0; ks < 2; ++ks) {
            half8 pa = *(const half8*)&Pl[w][c][32 * ks + 8 * g];
#pragma unroll
            for (int jd = 0; jd < 4; ++jd) {
                half8 vb = *(const half8*)&Vt[cur][16 * jd + c][32 * ks + 8 * g];
                accO[jd] = __builtin_amdgcn_mfma_f32_16x16x32_f16(
                    pa, vb, accO[jd], 0, 0, 0);
            }
        }
    }

    // epilogue: y[b, q, h*64 + d] = O / l
#pragma unroll
    for (int jd = 0; jd < 4; ++jd)
#pragma unroll
        for (int r = 0; r < 4; ++r) {
            int q = qt * 64 + w * 16 + 4 * g + r;
            y[((size_t)(b * TT + q)) * CC + h * HD + 16 * jd + c] =
                accO[jd][r] / lrow[r];
        }
}

extern "C" void kernel_launch(void* const* d_in, const int* in_sizes, int n_in,
                              void* d_out, int out_size, void* d_ws, size_t ws_size,
                              hipStream_t stream) {
    const int*   idx     = (const int*)d_in[0];
    const float* wte     = (const float*)d_in[1];
    const float* wpe     = (const float*)d_in[2];
    const float* ln1w    = (const float*)d_in[3];
    const float* ln1b    = (const float*)d_in[4];
    const float* qkvw    = (const float*)d_in[5];
    const float* qkvb    = (const float*)d_in[6];
    const float* projw   = (const float*)d_in[7];
    const float* projb   = (const float*)d_in[8];
    const float* ln2w    = (const float*)d_in[9];
    const float* ln2b    = (const float*)d_in[10];
    const float* fcw     = (const float*)d_in[11];
    const float* fcb     = (const float*)d_in[12];
    const float* fcprojw = (const float*)d_in[13];
    const float* fcprojb = (const float*)d_in[14];
    const float* lnfw    = (const float*)d_in[15];
    const float* lnfb    = (const float*)d_in[16];
    float* logits = (float*)d_out;

    // workspace layout (floats)
    float* ws = (float*)d_ws;
    const size_t xn = (size_t)MM * CC;          // 1,572,864
    float* x   = ws;                            // residual stream
    float* h   = x + xn;                        // LN output
    float* y   = h + xn;                        // attention output
    float* big = y + xn;                        // qkv (2048x2304) / fc act (2048x3072)
    float* qkv = big;
    float* hfc = big;

    const int M = MM;
    dim3 tb(256);

    // embedding
    {
        int n = (int)xn;
        embed_kernel<<<(n + 255) / 256, tb, 0, stream>>>(idx, wte, wpe, x, n);
    }

    const int nb_qkv    = (M / 128) * (3 * CC / 128);  // 16*18  = 288
    const int nb_proj   = (M / 64) * (CC / 64);        // 32*12  = 384
    const int nb_fc     = (M / 128) * (4 * CC / 128);  // 16*24  = 384
    const int nb_fcproj = (M / 64) * (CC / 64);        // 32*12  = 384
    const int nb_head   = (M / 128) * (VP / 128);      // 16*393 = 6288

    for (int l = 0; l < NL; ++l) {
        // LN1
        ln_kernel<<<M, tb, 0, stream>>>(x, ln1w + l * CC, ln1b + l * CC, h);
        // qkv = h @ qkvw^T + qkvb   (N = 2304)
        gemm_kernel<128, 128, false, false, false><<<dim3(nb_qkv), tb, 0, stream>>>(
            h, qkvw + (size_t)l * 3 * CC * CC, qkvb + (size_t)l * 3 * CC,
            nullptr, qkv, M, 3 * CC, CC);
        // attention (flash, q-tiles of 64)
        attn_kernel<<<dim3(BB * NH * (TT / 64)), tb, 0, stream>>>(qkv, y);
        // x = x + y @ projw^T + projb  (N = 768)
        gemm_kernel<64, 64, false, true, false><<<dim3(nb_proj), tb, 0, stream>>>(
            y, projw + (size_t)l * CC * CC, projb + (size_t)l * CC,
            x, x, M, CC, CC);
        // LN2
        ln_kernel<<<M, tb, 0, stream>>>(x, ln2w + l * CC, ln2b + l * CC, h);
        // hfc = gelu(h @ fcw^T + fcb)  (N = 3072)
        gemm_kernel<128, 128, true, false, false><<<dim3(nb_fc), tb, 0, stream>>>(
            h, fcw + (size_t)l * 4 * CC * CC, fcb + (size_t)l * 4 * CC,
            nullptr, hfc, M, 4 * CC, CC);
        // x = x + hfc @ fcprojw^T + fcprojb  (K = 3072)
        gemm_kernel<64, 64, false, true, false><<<dim3(nb_fcproj), tb, 0, stream>>>(
            hfc, fcprojw + (size_t)l * CC * 4 * CC, fcprojb + (size_t)l * CC,
            x, x, M, CC, 4 * CC);
    }

    // final LN
    ln_kernel<<<M, tb, 0, stream>>>(x, lnfw, lnfb, h);
    // logits = h @ wte^T  (N = 50304, no bias; NT stores keep wte in cache)
    gemm_kernel<128, 128, false, false, true><<<dim3(nb_head), tb, 0, stream>>>(
        h, wte, nullptr, nullptr, logits, M, VP, CC);
}